// Round 12
// baseline (311.012 us; speedup 1.0000x reference)
//
#include <hip/hip_runtime.h>
#include <math.h>

typedef _Float16 half8  __attribute__((ext_vector_type(8)));
typedef float    float4v __attribute__((ext_vector_type(4)));

constexpr int T_ = 1 << 18;            // hash table size per level
constexpr unsigned TMASK = T_ - 1;
constexpr unsigned PRIME = 2654435761u;

// ws layout:
//   [0, 23488)           : LDS-resident: W frags, biases, N_values, level offsets
//   [23488, 57280)       : packed v1/v2 table, f16x2 pairs per entry
//   [57344, +16MB)       : f16-packed v3 table
//   [XS_OFF, +8MB)       : spatially-sorted X (float2)
//   [IDX_OFF, +4MB)      : original index per sorted point (u32)
//   [HIST_OFF, +256KB)   : 64K bucket counters / offsets
constexpr int WFRAG_HALFS = 22 * 64 * 8;
constexpr int BIAS_FLOATS = 208;
constexpr int WS_BYTES    = 22528 + 240 * 4;   // 23488
constexpr int WS_UINT4    = WS_BYTES / 16;     // 1468
constexpr int V12_OFF     = 23488;
constexpr int V3T_OFF     = 57344;
constexpr size_t V3T_BYTES = (size_t)16 * T_ * 4;       // 16 MB
constexpr size_t XS_OFF    = (size_t)V3T_OFF + V3T_BYTES;
constexpr int NBUCK = 256 * 256;

// R12: cut L2 request count via spatial point bucketing. Surviving model:
// the wall is per-XCD L2 request service for L1-missing scattered reads
// (R3 win scaled with them; R8 L1-hot +32/pt free; R9 occupancy null; R11
// FETCH -83% but dur -8%). The hash xi^(yi*PRIME) is ROW-LOCAL: consecutive
// xi (fixed yi) share a 64B line (16 f16x2 entries). Bucket points into
// 256x256 cells (~16 pts/bucket) so each wave-tile's 16 points share ~5
// lines/level instead of 16 -> ~3x fewer L2 requests. Sort: hist + scan +
// scatter (one-off ~15us). Outputs scatter back to orig index (1 req/pt).
// Same per-point arithmetic -> absmax 0. Gated on ws_size; falls back to R11.
constexpr int BLK   = 256;                 // threads / block (4 waves)
constexpr int PTS_PER_BLOCK = 512;         // 4 waves x 8 tiles x 16 pts

struct Meta { float n[16]; float off[16]; };

// ---------------- prep: swizzle weights + pack v12 table ----------------
__global__ void prep_weights(const float* __restrict__ W1, const float* __restrict__ b1,
                             const float* __restrict__ W2, const float* __restrict__ b2,
                             const float* __restrict__ W3, const float* __restrict__ b3,
                             const float* __restrict__ W4, const float* __restrict__ b4,
                             const float2* __restrict__ table,
                             _Float16* __restrict__ wsW, float* __restrict__ wsB,
                             uint2* __restrict__ wsV, Meta mv)
{
    const int tid = threadIdx.x;
    const int bid = blockIdx.x;
    if (bid < 44) {
        const int e = bid * 256 + tid;
        const int frag = e >> 9;
        const int l    = (e >> 3) & 63;
        const int j    = e & 7;
        const int g = l >> 4, m = l & 15;
        const int u = j >> 2, r = j & 3;            // k-pos split for sigma swizzle
        float v;
        if (frag < 4) {                       // L1: W1 (32x64), identity k-map
            v = W1[(8*g + j) * 64 + 16*frag + m];
        } else if (frag < 12) {               // L2: rows = sigma_s(8g+j) = 32s+16u+4g+r
            const int s = (frag - 4) >> 2, t = (frag - 4) & 3;
            v = W2[(32*s + 16*u + 4*g + r) * 64 + 16*t + m];
        } else if (frag < 20) {               // L3: ditto
            const int s = (frag - 12) >> 2, t = (frag - 12) & 3;
            v = W3[(32*s + 16*u + 4*g + r) * 64 + 16*t + m];
        } else {                              // L4 (64x3): ditto, pad n>=3 with 0
            const int s = frag - 20;
            v = (m < 3) ? W4[(32*s + 16*u + 4*g + r) * 3 + m] : 0.f;
        }
        wsW[e] = (_Float16)v;
    } else if (bid == 44) {
        if (tid < 64) { wsB[tid] = b1[tid]; wsB[64 + tid] = b2[tid]; wsB[128 + tid] = b3[tid]; }
        else if (tid < 80)  { const int r2 = tid - 64; wsB[192 + r2] = (r2 < 3) ? b4[r2] : 0.f; }
        else if (tid < 96)  wsB[BIAS_FLOATS + (tid - 80)] = mv.n[tid - 80];
        else if (tid < 112) wsB[BIAS_FLOATS + 16 + (tid - 96)] = mv.off[tid - 96];
    } else {
        const int e = (bid - 45) * 256 + tid;
        const int total = (int)mv.off[15] + (int)mv.n[15] + 1;   // 4194
        if (e < total) {
            int l = 0;
            #pragma unroll
            for (int k = 1; k < 16; ++k) if (e >= (int)mv.off[k]) l = k;
            const int i = e - (int)mv.off[l];
            const float2* tl = table + (size_t)l * T_;
            const float2 b = tl[((unsigned)i * PRIME) & TMASK];  // v1 source
            const float2 a = tl[i];                              // v2 source
            union { _Float16 h[2]; unsigned u; } p0, p1;
            p0.h[0] = (_Float16)b.x; p0.h[1] = (_Float16)b.y;
            p1.h[0] = (_Float16)a.x; p1.h[1] = (_Float16)a.y;
            wsV[e] = uint2{p0.u, p1.u};
        }
    }
}

// ---------------- prep: f16-pack the full v3 table (32 MB -> 16 MB) ----------------
__global__ void prep_table_f16(const float2* __restrict__ table, unsigned* __restrict__ t16)
{
    const size_t i = (size_t)blockIdx.x * 256 + threadIdx.x;   // grid == 16*T_ exactly
    const float2 v = table[i];
    union { _Float16 h[2]; unsigned u; } p;
    p.h[0] = (_Float16)v.x; p.h[1] = (_Float16)v.y;
    t16[i] = p.u;
}

// ---------------- sort: 256x256 spatial bucketing ----------------
__device__ __forceinline__ int bucket_key(const float2 p) {
    int kx = (int)(p.x * 256.f); kx = kx > 255 ? 255 : kx;
    int ky = (int)(p.y * 256.f); ky = ky > 255 ? 255 : ky;
    return (ky << 8) | kx;
}

__global__ void s_hist(const float2* __restrict__ X, unsigned* __restrict__ hist, int npts)
{
    const int i = blockIdx.x * 256 + threadIdx.x;
    if (i < npts) atomicAdd(&hist[bucket_key(X[i])], 1u);
}

__global__ __launch_bounds__(1024) void s_scan(unsigned* __restrict__ hist)
{
    __shared__ unsigned part[1024];
    const int t = threadIdx.x;
    unsigned sum = 0;
    for (int k = 0; k < 64; ++k) sum += hist[t * 64 + k];
    part[t] = sum;
    __syncthreads();
    for (int d = 1; d < 1024; d <<= 1) {
        const unsigned v = (t >= d) ? part[t - d] : 0u;
        __syncthreads();
        part[t] += v;
        __syncthreads();
    }
    unsigned run = (t == 0) ? 0u : part[t - 1];
    for (int k = 0; k < 64; ++k) {
        const unsigned c = hist[t * 64 + k];
        hist[t * 64 + k] = run;
        run += c;
    }
}

__global__ void s_scatter(const float2* __restrict__ X, unsigned* __restrict__ off,
                          float2* __restrict__ Xs, unsigned* __restrict__ idx, int npts)
{
    const int i = blockIdx.x * 256 + threadIdx.x;
    if (i < npts) {
        const float2 p = X[i];
        const unsigned d = atomicAdd(&off[bucket_key(p)], 1u);
        Xs[d] = p;
        idx[d] = (unsigned)i;
    }
}

// ---------------- main fused kernel ----------------
struct Gather {
    float2   v3f[4];
    unsigned v3u[4];
    unsigned v1[4];
    unsigned v2[4];
};

template<int MODE>   // 0 = f32 table, 1 = f16 table, 2 = f16 + sorted points
__device__ __forceinline__ void issue_gather(Gather& G, const float2 xy,
                                             const float2* __restrict__ table,
                                             const unsigned* __restrict__ t16,
                                             const unsigned* __restrict__ gV12,
                                             const float (&nvq)[4], const int (&offq)[4],
                                             const int g)
{
    #pragma unroll
    for (int q = 0; q < 4; ++q) {
        const float n = nvq[q];
        const float xs = xy.x * n, ys = xy.y * n;
        const int xi = (int)floorf(xs);
        const int yi = (int)floorf(ys);
        const unsigned yp = (unsigned)yi * PRIME;
        const size_t idx = (size_t)(4*g + q) * T_ + (((unsigned)xi ^ yp) & TMASK);
        if constexpr (MODE >= 1) G.v3u[q] = t16[idx];
        else                     G.v3f[q] = table[idx];
        G.v1[q] = gV12[2*(offq[q] + yi) + 0];
        G.v2[q] = gV12[2*(offq[q] + xi) + 1];
    }
}

template<int MODE>
__device__ __forceinline__ half8 make_feat(const float2 xy, const Gather& G,
                                           const float (&nvq)[4],
                                           const float2 (&v0c)[4])
{
    half8 feat;
    #pragma unroll
    for (int q = 0; q < 4; ++q) {
        const float n = nvq[q];
        const float xs = xy.x * n, ys = xy.y * n;
        const float xf = floorf(xs), yf = floorf(ys);
        const float fx = xs - xf, fy = ys - yf;
        union { unsigned u; _Float16 h[2]; } u1, u2, u3;
        u1.u = G.v1[q]; u2.u = G.v2[q];
        float v3x, v3y;
        if constexpr (MODE >= 1) { u3.u = G.v3u[q]; v3x = (float)u3.h[0]; v3y = (float)u3.h[1]; }
        else                     { v3x = G.v3f[q].x; v3y = G.v3f[q].y; }
        const float cx = 1.f - fx, cy = 1.f - fy;
        const float w0 = cx*cy, w1 = cx*fy, w2 = fx*cy, w3 = fx*fy;
        feat[2*q+0] = (_Float16)(w0*v0c[q].x + w1*(float)u1.h[0] + w2*(float)u2.h[0] + w3*v3x);
        feat[2*q+1] = (_Float16)(w0*v0c[q].y + w1*(float)u1.h[1] + w2*(float)u2.h[1] + w3*v3y);
    }
    return feat;
}

// in-register layer handoff: leaky-relu + f16, a_s[4u+r] = f16(leaky(acc[2s+u][r]))
__device__ __forceinline__ void repack(const float4v (&acc)[4], half8& a0, half8& a1)
{
    #pragma unroll
    for (int u = 0; u < 2; ++u)
        #pragma unroll
        for (int r = 0; r < 4; ++r) {
            const float v0 = acc[u][r];
            const float v1 = acc[2 + u][r];
            a0[4*u + r] = (_Float16)(v0 > 0.f ? v0 : 0.01f * v0);
            a1[4*u + r] = (_Float16)(v1 > 0.f ? v1 : 0.01f * v1);
        }
}

template<int MODE>
__global__ __launch_bounds__(BLK)
void fused_hashnerf_mfma(const float2* __restrict__ X,
                         const float2* __restrict__ table,
                         const uint4* __restrict__ ws,
                         const unsigned* __restrict__ idx,
                         float* __restrict__ out)
{
    __shared__ uint4 sRaw[WS_UINT4];           // W frags (f16) + biases + meta (23.5 KB)

    const int tid = threadIdx.x;
    for (int i = tid; i < WS_UINT4; i += BLK) sRaw[i] = ws[i];
    __syncthreads();

    const _Float16* Wl = (const _Float16*)sRaw;
    const float*    Bl = (const float*)(sRaw + (22528 / 16));
    const unsigned* gV12 = (const unsigned*)((const char*)ws + V12_OFF);
    const unsigned* t16  = (const unsigned*)((const char*)ws + V3T_OFF);

    const int wave = tid >> 6, lane = tid & 63;
    const int g = lane >> 4, c = lane & 15;

    float4v b1f[4], b2f[4], b3f[4], b4f;
    #pragma unroll
    for (int t = 0; t < 4; ++t) {
        b1f[t] = *(const float4v*)(Bl +       16*t + 4*g);
        b2f[t] = *(const float4v*)(Bl +  64 + 16*t + 4*g);
        b3f[t] = *(const float4v*)(Bl + 128 + 16*t + 4*g);
    }
    b4f = *(const float4v*)(Bl + 192 + 4*g);
    float nvq[4];
    int   offq[4];
    #pragma unroll
    for (int q = 0; q < 4; ++q) {
        nvq[q]  = Bl[BIAS_FLOATS + 4*g + q];
        offq[q] = (int)Bl[BIAS_FLOATS + 16 + 4*g + q];
    }

    const int base_pt = blockIdx.x * PTS_PER_BLOCK + wave * 128;

    float2 xy[8];
    #pragma unroll
    for (int it = 0; it < 8; ++it) xy[it] = X[base_pt + it*16 + c];

    float2 v0c[4];
    #pragma unroll
    for (int q = 0; q < 4; ++q) v0c[q] = table[(size_t)(4*g + q) * T_];

    Gather G0, G1, G2;
    issue_gather<MODE>(G0, xy[0], table, t16, gV12, nvq, offq, g);
    issue_gather<MODE>(G1, xy[1], table, t16, gV12, nvq, offq, g);

    #pragma unroll
    for (int it = 0; it < 8; ++it) {
        Gather& Gc = (it % 3 == 0) ? G0 : (it % 3 == 1) ? G1 : G2;
        Gather& Gn = ((it + 2) % 3 == 0) ? G0 : ((it + 2) % 3 == 1) ? G1 : G2;

        const half8 feat = make_feat<MODE>(xy[it], Gc, nvq, v0c);

        if (it < 6) issue_gather<MODE>(Gn, xy[it+2], table, t16, gV12, nvq, offq, g);
        __builtin_amdgcn_sched_barrier(0);

        // ---- L1 ----
        float4v acc[4];
        #pragma unroll
        for (int t = 0; t < 4; ++t) {
            const half8 wf = *(const half8*)(Wl + (t*64 + lane)*8);
            acc[t] = __builtin_amdgcn_mfma_f32_16x16x32_f16(wf, feat, b1f[t], 0, 0, 0);
        }

        // ---- L2 (in-register handoff, sigma-swizzled weights) ----
        half8 a0, a1;
        repack(acc, a0, a1);
        #pragma unroll
        for (int t = 0; t < 4; ++t) {
            const half8 w0f = *(const half8*)(Wl + ((4 + t)*64 + lane)*8);
            const half8 w1f = *(const half8*)(Wl + ((8 + t)*64 + lane)*8);
            float4v a = __builtin_amdgcn_mfma_f32_16x16x32_f16(w0f, a0, b2f[t], 0, 0, 0);
            acc[t]    = __builtin_amdgcn_mfma_f32_16x16x32_f16(w1f, a1, a,      0, 0, 0);
        }

        // ---- L3 ----
        repack(acc, a0, a1);
        #pragma unroll
        for (int t = 0; t < 4; ++t) {
            const half8 w0f = *(const half8*)(Wl + ((12 + t)*64 + lane)*8);
            const half8 w1f = *(const half8*)(Wl + ((16 + t)*64 + lane)*8);
            float4v a = __builtin_amdgcn_mfma_f32_16x16x32_f16(w0f, a0, b3f[t], 0, 0, 0);
            acc[t]    = __builtin_amdgcn_mfma_f32_16x16x32_f16(w1f, a1, a,      0, 0, 0);
        }

        // ---- L4: n_out = 0..2 live in lanes g==0 ----
        repack(acc, a0, a1);
        const half8 w40 = *(const half8*)(Wl + (20*64 + lane)*8);
        const half8 w41 = *(const half8*)(Wl + (21*64 + lane)*8);
        float4v o = __builtin_amdgcn_mfma_f32_16x16x32_f16(w40, a0, b4f, 0, 0, 0);
        o         = __builtin_amdgcn_mfma_f32_16x16x32_f16(w41, a1, o,   0, 0, 0);
        if (g == 0) {
            const int p = base_pt + it * 16 + c;
            size_t oi;
            if constexpr (MODE == 2) oi = idx[p];
            else                     oi = (size_t)p;
            float* op = out + 3 * oi;
            op[0] = fmaxf(o[0], 0.f);
            op[1] = fmaxf(o[1], 0.f);
            op[2] = fmaxf(o[2], 0.f);
        }
    }
}

extern "C" void kernel_launch(void* const* d_in, const int* in_sizes, int n_in,
                              void* d_out, int out_size, void* d_ws, size_t ws_size,
                              hipStream_t stream) {
    const float2* X     = (const float2*)d_in[0];
    const float2* table = (const float2*)d_in[1];
    const float*  W1    = (const float*)d_in[2];
    const float*  b1    = (const float*)d_in[3];
    const float*  W2    = (const float*)d_in[4];
    const float*  b2    = (const float*)d_in[5];
    const float*  W3    = (const float*)d_in[6];
    const float*  b3    = (const float*)d_in[7];
    const float*  W4    = (const float*)d_in[8];
    const float*  b4    = (const float*)d_in[9];
    float* out          = (float*)d_out;

    const int npts = in_sizes[0] / 2;

    Meta mv;
    const double bg = exp((log(1024.0) - log(16.0)) / 15.0);
    int acc = 0;
    for (int l = 0; l < 16; ++l) {
        const float nl = floorf((float)(16.0 * pow(bg, (double)l)));
        mv.n[l]   = nl;
        mv.off[l] = (float)acc;
        acc += (int)nl + 1;
    }

    _Float16* wsW = (_Float16*)d_ws;
    float*    wsB = (float*)((char*)d_ws + 22528);
    uint2*    wsV = (uint2*)((char*)d_ws + V12_OFF);
    unsigned* t16 = (unsigned*)((char*)d_ws + V3T_OFF);

    const size_t idx_off  = XS_OFF + (size_t)npts * 8;
    const size_t hist_off = idx_off + (size_t)npts * 4;
    const size_t need_sorted = hist_off + (size_t)NBUCK * 4;

    float2*   Xs   = (float2*)((char*)d_ws + XS_OFF);
    unsigned* idx  = (unsigned*)((char*)d_ws + idx_off);
    unsigned* hist = (unsigned*)((char*)d_ws + hist_off);

    const int grid = npts / PTS_PER_BLOCK;
    const int pblk = (npts + 255) / 256;

    prep_weights<<<62, 256, 0, stream>>>(W1, b1, W2, b2, W3, b3, W4, b4, table,
                                         wsW, wsB, wsV, mv);

    if (ws_size >= need_sorted) {
        prep_table_f16<<<16 * T_ / 256, 256, 0, stream>>>(table, t16);
        hipMemsetAsync(hist, 0, (size_t)NBUCK * 4, stream);
        s_hist<<<pblk, 256, 0, stream>>>(X, hist, npts);
        s_scan<<<1, 1024, 0, stream>>>(hist);
        s_scatter<<<pblk, 256, 0, stream>>>(X, hist, Xs, idx, npts);
        fused_hashnerf_mfma<2><<<grid, BLK, 0, stream>>>(Xs, table, (const uint4*)d_ws, idx, out);
    } else if (ws_size >= (size_t)V3T_OFF + V3T_BYTES) {
        prep_table_f16<<<16 * T_ / 256, 256, 0, stream>>>(table, t16);
        fused_hashnerf_mfma<1><<<grid, BLK, 0, stream>>>(X, table, (const uint4*)d_ws, nullptr, out);
    } else {
        fused_hashnerf_mfma<0><<<grid, BLK, 0, stream>>>(X, table, (const uint4*)d_ws, nullptr, out);
    }
}

// Round 13
// 208.924 us; speedup vs baseline: 1.4886x; 1.4886x over previous
//
#include <hip/hip_runtime.h>
#include <math.h>

typedef _Float16 half8  __attribute__((ext_vector_type(8)));
typedef float    float4v __attribute__((ext_vector_type(4)));

constexpr int T_ = 1 << 18;            // hash table size per level
constexpr unsigned TMASK = T_ - 1;
constexpr unsigned PRIME = 2654435761u;

// ws layout:
//   [0, 23552)       : LDS-resident: W frags, biases, N_values, v12 offsets, tc bases
//   [23552, 57104)   : packed v1/v2 table, f16x2 pairs per entry
//   [57344, +~4.1MB) : tc table: levels 0-12 COMPACT direct-indexed (dense
//                      (N_l+1)^2 per level), levels 13-15 hashed, all f16x2
constexpr int WFRAG_HALFS = 22 * 64 * 8;
constexpr int BIAS_FLOATS = 208;
constexpr int WS_BYTES    = 22528 + 256 * 4;   // 23552 (LDS-resident part)
constexpr int WS_UINT4    = WS_BYTES / 16;     // 1472
constexpr int V12_OFF     = 23552;
constexpr int TC_OFF      = 57344;             // 64B-aligned

// R13: footprint compaction, no sort. R12 proved locality is worth 47us of
// main-kernel time but ANY physical regroup costs >=60us (atomics+scatter) --
// net negative on the scored total (311 vs 213). Revert to 3 dispatches.
// Surviving cost model: L1-resident gathers free (R8), L2 scattered requests
// are the wall. The hash sprays level l's (N_l+1)^2 occupied cells over a
// full 1MB slice -> level 0-4's ~5.5K entries occupy ~5.5K lines. Compact
// levels 0-12 into dense direct-indexed tables (values precomputed per cell,
// bit-identical); levels 0-4 (~22KB) become L1-resident -> free; 5-12 dense
// in L2; total tc ~5MB (vs 16MB) -> near-zero HBM refill. Levels 13-15 keep
// the hash (their (N+1)^2 > T). Also: pipeline now carries fx,fy (VALU dedupe).
constexpr int BLK   = 256;                 // threads / block (4 waves)
constexpr int PTS_PER_BLOCK = 512;         // 4 waves x 8 tiles x 16 pts

struct Meta { float n[16]; float off[16]; float cb[16]; };

// ---------------- prep: swizzle weights + pack v12 table ----------------
__global__ void prep_weights(const float* __restrict__ W1, const float* __restrict__ b1,
                             const float* __restrict__ W2, const float* __restrict__ b2,
                             const float* __restrict__ W3, const float* __restrict__ b3,
                             const float* __restrict__ W4, const float* __restrict__ b4,
                             const float2* __restrict__ table,
                             _Float16* __restrict__ wsW, float* __restrict__ wsB,
                             uint2* __restrict__ wsV, Meta mv)
{
    const int tid = threadIdx.x;
    const int bid = blockIdx.x;
    if (bid < 44) {
        const int e = bid * 256 + tid;
        const int frag = e >> 9;
        const int l    = (e >> 3) & 63;
        const int j    = e & 7;
        const int g = l >> 4, m = l & 15;
        const int u = j >> 2, r = j & 3;            // k-pos split for sigma swizzle
        float v;
        if (frag < 4) {                       // L1: W1 (32x64), identity k-map
            v = W1[(8*g + j) * 64 + 16*frag + m];
        } else if (frag < 12) {               // L2: rows = sigma_s(8g+j) = 32s+16u+4g+r
            const int s = (frag - 4) >> 2, t = (frag - 4) & 3;
            v = W2[(32*s + 16*u + 4*g + r) * 64 + 16*t + m];
        } else if (frag < 20) {               // L3: ditto
            const int s = (frag - 12) >> 2, t = (frag - 12) & 3;
            v = W3[(32*s + 16*u + 4*g + r) * 64 + 16*t + m];
        } else {                              // L4 (64x3): ditto, pad n>=3 with 0
            const int s = frag - 20;
            v = (m < 3) ? W4[(32*s + 16*u + 4*g + r) * 3 + m] : 0.f;
        }
        wsW[e] = (_Float16)v;
    } else if (bid == 44) {
        if (tid < 64) { wsB[tid] = b1[tid]; wsB[64 + tid] = b2[tid]; wsB[128 + tid] = b3[tid]; }
        else if (tid < 80)  { const int r2 = tid - 64; wsB[192 + r2] = (r2 < 3) ? b4[r2] : 0.f; }
        else if (tid < 96)  wsB[BIAS_FLOATS +      (tid - 80)] = mv.n[tid - 80];
        else if (tid < 112) wsB[BIAS_FLOATS + 16 + (tid - 96)] = mv.off[tid - 96];
        else if (tid < 128) wsB[BIAS_FLOATS + 32 + (tid - 112)] = mv.cb[tid - 112];
    } else {
        // packed v12 table: entry e -> (level l, index i)
        const int e = (bid - 45) * 256 + tid;
        const int total = (int)mv.off[15] + (int)mv.n[15] + 1;   // 4194
        if (e < total) {
            int l = 0;
            #pragma unroll
            for (int k = 1; k < 16; ++k) if (e >= (int)mv.off[k]) l = k;
            const int i = e - (int)mv.off[l];
            const float2* tl = table + (size_t)l * T_;
            const float2 b = tl[((unsigned)i * PRIME) & TMASK];  // v1 source
            const float2 a = tl[i];                              // v2 source
            union { _Float16 h[2]; unsigned u; } p0, p1;
            p0.h[0] = (_Float16)b.x; p0.h[1] = (_Float16)b.y;
            p1.h[0] = (_Float16)a.x; p1.h[1] = (_Float16)a.y;
            wsV[e] = uint2{p0.u, p1.u};
        }
    }
}

// ---------------- prep: build compact+hashed tc table (f16) ----------------
__global__ void prep_tc(const float2* __restrict__ table, unsigned* __restrict__ tc,
                        Meta mv, int total)
{
    const int e = blockIdx.x * 256 + threadIdx.x;
    if (e >= total) return;
    int l = 0;
    #pragma unroll
    for (int k = 1; k < 16; ++k) if (e >= (int)mv.cb[k]) l = k;
    const int rel = e - (int)mv.cb[l];
    unsigned src;
    if (l <= 12) {                               // compact: rel = yi*p + xi
        const int p  = (int)mv.n[l] + 1;
        const int yi = rel / p, xi = rel - yi * p;
        src = ((unsigned)xi ^ ((unsigned)yi * PRIME)) & TMASK;
    } else {                                     // hashed: identity
        src = (unsigned)rel;
    }
    const float2 v = table[(size_t)l * T_ + src];
    union { _Float16 h[2]; unsigned u; } pk;
    pk.h[0] = (_Float16)v.x; pk.h[1] = (_Float16)v.y;
    tc[e] = pk.u;
}

// ---------------- main fused kernel ----------------
struct Gather {                // pipeline state; fx/fy carried (VALU dedupe)
    float    fx[4], fy[4];
    unsigned v3u[4];           // MODE 3: f16x2 from tc
    float2   v3f[4];           // MODE 0: f32 from raw table
    unsigned v1[4], v2[4];
};

template<int MODE>   // 0 = raw f32 table (fallback), 3 = compact tc table
__device__ __forceinline__ void issue_gather(Gather& G, const float2 xy,
                                             const float2* __restrict__ table,
                                             const unsigned* __restrict__ tc,
                                             const unsigned* __restrict__ gV12,
                                             const float (&nvq)[4], const int (&offq)[4],
                                             const unsigned (&cbq)[4], const int (&pq)[4],
                                             const int g)
{
    #pragma unroll
    for (int q = 0; q < 4; ++q) {
        const float n = nvq[q];
        const float xs = xy.x * n, ys = xy.y * n;
        const float xf = floorf(xs), yf = floorf(ys);
        G.fx[q] = xs - xf; G.fy[q] = ys - yf;
        const int xi = (int)xf, yi = (int)yf;
        if constexpr (MODE == 3) {
            unsigned idx;
            // lv = 4g+q <= 12 -> compact (q==0: always; q>=1: g<3)
            if (q == 0 || g < 3) idx = cbq[q] + (unsigned)(yi * pq[q] + xi);
            else                 idx = cbq[q] + (((unsigned)xi ^ ((unsigned)yi * PRIME)) & TMASK);
            G.v3u[q] = tc[idx];
        } else {
            const unsigned yp = (unsigned)yi * PRIME;
            G.v3f[q] = table[(size_t)(4*g + q) * T_ + (((unsigned)xi ^ yp) & TMASK)];
        }
        G.v1[q] = gV12[2*(offq[q] + yi) + 0];
        G.v2[q] = gV12[2*(offq[q] + xi) + 1];
    }
}

template<int MODE>
__device__ __forceinline__ half8 make_feat(const Gather& G, const float2 (&v0c)[4])
{
    half8 feat;
    #pragma unroll
    for (int q = 0; q < 4; ++q) {
        const float fx = G.fx[q], fy = G.fy[q];
        union { unsigned u; _Float16 h[2]; } u1, u2, u3;
        u1.u = G.v1[q]; u2.u = G.v2[q];
        float v3x, v3y;
        if constexpr (MODE == 3) { u3.u = G.v3u[q]; v3x = (float)u3.h[0]; v3y = (float)u3.h[1]; }
        else                     { v3x = G.v3f[q].x; v3y = G.v3f[q].y; }
        const float cx = 1.f - fx, cy = 1.f - fy;
        const float w0 = cx*cy, w1 = cx*fy, w2 = fx*cy, w3 = fx*fy;
        feat[2*q+0] = (_Float16)(w0*v0c[q].x + w1*(float)u1.h[0] + w2*(float)u2.h[0] + w3*v3x);
        feat[2*q+1] = (_Float16)(w0*v0c[q].y + w1*(float)u1.h[1] + w2*(float)u2.h[1] + w3*v3y);
    }
    return feat;
}

// in-register layer handoff: leaky-relu + f16, a_s[4u+r] = f16(leaky(acc[2s+u][r]))
__device__ __forceinline__ void repack(const float4v (&acc)[4], half8& a0, half8& a1)
{
    #pragma unroll
    for (int u = 0; u < 2; ++u)
        #pragma unroll
        for (int r = 0; r < 4; ++r) {
            const float v0 = acc[u][r];
            const float v1 = acc[2 + u][r];
            a0[4*u + r] = (_Float16)(v0 > 0.f ? v0 : 0.01f * v0);
            a1[4*u + r] = (_Float16)(v1 > 0.f ? v1 : 0.01f * v1);
        }
}

template<int MODE>
__global__ __launch_bounds__(BLK)
void fused_hashnerf_mfma(const float2* __restrict__ X,
                         const float2* __restrict__ table,
                         const uint4* __restrict__ ws,
                         float* __restrict__ out)
{
    __shared__ uint4 sRaw[WS_UINT4];           // W frags (f16) + biases + meta (23.5 KB)

    const int tid = threadIdx.x;
    for (int i = tid; i < WS_UINT4; i += BLK) sRaw[i] = ws[i];
    __syncthreads();

    const _Float16* Wl = (const _Float16*)sRaw;
    const float*    Bl = (const float*)(sRaw + (22528 / 16));
    const unsigned* gV12 = (const unsigned*)((const char*)ws + V12_OFF);
    const unsigned* tc   = (const unsigned*)((const char*)ws + TC_OFF);

    const int wave = tid >> 6, lane = tid & 63;
    const int g = lane >> 4, c = lane & 15;

    float4v b1f[4], b2f[4], b3f[4], b4f;
    #pragma unroll
    for (int t = 0; t < 4; ++t) {
        b1f[t] = *(const float4v*)(Bl +       16*t + 4*g);
        b2f[t] = *(const float4v*)(Bl +  64 + 16*t + 4*g);
        b3f[t] = *(const float4v*)(Bl + 128 + 16*t + 4*g);
    }
    b4f = *(const float4v*)(Bl + 192 + 4*g);
    float    nvq[4];
    int      offq[4];
    unsigned cbq[4];
    int      pq[4];
    #pragma unroll
    for (int q = 0; q < 4; ++q) {
        nvq[q]  = Bl[BIAS_FLOATS +      4*g + q];
        offq[q] = (int)Bl[BIAS_FLOATS + 16 + 4*g + q];
        cbq[q]  = (unsigned)Bl[BIAS_FLOATS + 32 + 4*g + q];
        pq[q]   = (int)nvq[q] + 1;
    }

    const int base_pt = blockIdx.x * PTS_PER_BLOCK + wave * 128;

    float2 xy[8];
    #pragma unroll
    for (int it = 0; it < 8; ++it) xy[it] = X[base_pt + it*16 + c];

    // per-level constant corner (0,0): v0 = table[lv*T + 0] (f32, exact)
    float2 v0c[4];
    #pragma unroll
    for (int q = 0; q < 4; ++q) v0c[q] = table[(size_t)(4*g + q) * T_];

    Gather G0, G1, G2;
    issue_gather<MODE>(G0, xy[0], table, tc, gV12, nvq, offq, cbq, pq, g);
    issue_gather<MODE>(G1, xy[1], table, tc, gV12, nvq, offq, cbq, pq, g);

    #pragma unroll
    for (int it = 0; it < 8; ++it) {
        Gather& Gc = (it % 3 == 0) ? G0 : (it % 3 == 1) ? G1 : G2;
        Gather& Gn = ((it + 2) % 3 == 0) ? G0 : ((it + 2) % 3 == 1) ? G1 : G2;

        const half8 feat = make_feat<MODE>(Gc, v0c);

        if (it < 6) issue_gather<MODE>(Gn, xy[it+2], table, tc, gV12, nvq, offq, cbq, pq, g);
        __builtin_amdgcn_sched_barrier(0);

        // ---- L1 ----
        float4v acc[4];
        #pragma unroll
        for (int t = 0; t < 4; ++t) {
            const half8 wf = *(const half8*)(Wl + (t*64 + lane)*8);
            acc[t] = __builtin_amdgcn_mfma_f32_16x16x32_f16(wf, feat, b1f[t], 0, 0, 0);
        }

        // ---- L2 (in-register handoff, sigma-swizzled weights) ----
        half8 a0, a1;
        repack(acc, a0, a1);
        #pragma unroll
        for (int t = 0; t < 4; ++t) {
            const half8 w0f = *(const half8*)(Wl + ((4 + t)*64 + lane)*8);
            const half8 w1f = *(const half8*)(Wl + ((8 + t)*64 + lane)*8);
            float4v a = __builtin_amdgcn_mfma_f32_16x16x32_f16(w0f, a0, b2f[t], 0, 0, 0);
            acc[t]    = __builtin_amdgcn_mfma_f32_16x16x32_f16(w1f, a1, a,      0, 0, 0);
        }

        // ---- L3 ----
        repack(acc, a0, a1);
        #pragma unroll
        for (int t = 0; t < 4; ++t) {
            const half8 w0f = *(const half8*)(Wl + ((12 + t)*64 + lane)*8);
            const half8 w1f = *(const half8*)(Wl + ((16 + t)*64 + lane)*8);
            float4v a = __builtin_amdgcn_mfma_f32_16x16x32_f16(w0f, a0, b3f[t], 0, 0, 0);
            acc[t]    = __builtin_amdgcn_mfma_f32_16x16x32_f16(w1f, a1, a,      0, 0, 0);
        }

        // ---- L4: n_out = 0..2 live in lanes g==0 ----
        repack(acc, a0, a1);
        const half8 w40 = *(const half8*)(Wl + (20*64 + lane)*8);
        const half8 w41 = *(const half8*)(Wl + (21*64 + lane)*8);
        float4v o = __builtin_amdgcn_mfma_f32_16x16x32_f16(w40, a0, b4f, 0, 0, 0);
        o         = __builtin_amdgcn_mfma_f32_16x16x32_f16(w41, a1, o,   0, 0, 0);
        if (g == 0) {
            float* op = out + (size_t)3 * (base_pt + it * 16 + c);
            op[0] = fmaxf(o[0], 0.f);
            op[1] = fmaxf(o[1], 0.f);
            op[2] = fmaxf(o[2], 0.f);
        }
    }
}

extern "C" void kernel_launch(void* const* d_in, const int* in_sizes, int n_in,
                              void* d_out, int out_size, void* d_ws, size_t ws_size,
                              hipStream_t stream) {
    const float2* X     = (const float2*)d_in[0];
    const float2* table = (const float2*)d_in[1];
    const float*  W1    = (const float*)d_in[2];
    const float*  b1    = (const float*)d_in[3];
    const float*  W2    = (const float*)d_in[4];
    const float*  b2    = (const float*)d_in[5];
    const float*  W3    = (const float*)d_in[6];
    const float*  b3    = (const float*)d_in[7];
    const float*  W4    = (const float*)d_in[8];
    const float*  b4    = (const float*)d_in[9];
    float* out          = (float*)d_out;

    const int npts = in_sizes[0] / 2;

    // N_l = floor(float32(16 * b^l)); off = v12 prefix; cb = tc-table prefix
    // (levels 0-12: (N_l+1)^2 dense, levels 13-15: T_ hashed).
    Meta mv;
    const double bg = exp((log(1024.0) - log(16.0)) / 15.0);
    int acc = 0;
    for (int l = 0; l < 16; ++l) {
        const float nl = floorf((float)(16.0 * pow(bg, (double)l)));
        mv.n[l]   = nl;
        mv.off[l] = (float)acc;
        acc += (int)nl + 1;
    }
    unsigned cbacc = 0;
    for (int l = 0; l < 16; ++l) {
        mv.cb[l] = (float)cbacc;
        const int p = (int)mv.n[l] + 1;
        cbacc += (l <= 12) ? (unsigned)(p * p) : (unsigned)T_;
    }
    const unsigned total_tc = cbacc;           // ~1.0M entries, ~4.1 MB

    _Float16* wsW = (_Float16*)d_ws;
    float*    wsB = (float*)((char*)d_ws + 22528);
    uint2*    wsV = (uint2*)((char*)d_ws + V12_OFF);
    unsigned* tc  = (unsigned*)((char*)d_ws + TC_OFF);

    const int grid = npts / PTS_PER_BLOCK;

    prep_weights<<<62, 256, 0, stream>>>(W1, b1, W2, b2, W3, b3, W4, b4, table,
                                         wsW, wsB, wsV, mv);

    if (ws_size >= (size_t)TC_OFF + (size_t)total_tc * 4) {
        prep_tc<<<(int)((total_tc + 255) / 256), 256, 0, stream>>>(table, tc, mv, (int)total_tc);
        fused_hashnerf_mfma<3><<<grid, BLK, 0, stream>>>(X, table, (const uint4*)d_ws, out);
    } else {
        fused_hashnerf_mfma<0><<<grid, BLK, 0, stream>>>(X, table, (const uint4*)d_ws, out);
    }
}